// Round 5
// baseline (482.239 us; speedup 1.0000x reference)
//
#include <hip/hip_runtime.h>

#define D 64

__device__ __forceinline__ float lane_bcast(float v, int k) {
    return __int_as_float(__builtin_amdgcn_readlane(__float_as_int(v), k));
}

// ---------------- build: per-node linked list + degree count ----------------
// edge2[e] = {src, next}; one 8B scattered read per hop in fill.

__global__ void build_kernel(const int* __restrict__ ei, int* __restrict__ head,
                             int2* __restrict__ edge2, int* __restrict__ cnt, int E) {
    int e = blockIdx.x * blockDim.x + threadIdx.x;
    if (e < E) {
        int src = ei[e];
        int dst = ei[E + e];
        int prev = atomicExch(&head[dst], e);
        edge2[e] = make_int2(src, prev);
        atomicAdd(&cnt[dst], 1);
    }
}

// pure wave-scan bump allocator over padded degrees (pad to multiple of 8)
__global__ void alloc_kernel(const int* __restrict__ cnt, int* __restrict__ beg,
                             int* __restrict__ total, int N) {
    int i = blockIdx.x * blockDim.x + threadIdx.x;
    int lane = threadIdx.x & 63;
    int c = (i < N) ? ((cnt[i] + 7) & ~7) : 0;
    int p = c;
#pragma unroll
    for (int o = 1; o < 64; o <<= 1) {
        int u = __shfl_up(p, o, 64);
        if (lane >= o) p += u;
    }
    int wavetot = __shfl(p, 63, 64);
    int base = 0;
    if (lane == 63) base = atomicAdd(total, wavetot);
    base = __shfl(base, 63, 64);
    if (i < N) beg[i] = base + p - c;
}

// thread per node: walk chain, write contiguous slice, pad to x8 with first src
__global__ void fill_kernel(const int2* __restrict__ edge2, const int* __restrict__ head,
                            const int* __restrict__ beg_, const int* __restrict__ cnt_,
                            int* __restrict__ srclist, int N) {
    int i = blockIdx.x * blockDim.x + threadIdx.x;
    if (i >= N) return;
    int deg = cnt_[i];
    if (deg == 0) return;
    int b = beg_[i];
    int p = b;
    int e = head[i];
    int2 sn = edge2[e];
    int s_first = sn.x;
    for (;;) {
        srclist[p++] = sn.x;
        e = sn.y;
        if (e < 0) break;
        sn = edge2[e];
    }
    int pe = b + ((deg + 7) & ~7);
    for (; p < pe; ++p) srclist[p] = s_first;
}

// ---------------- fused SAGE layer ----------------
// out[n] = [relu]( mean_{s in N(n)} in[s] @ Wl^T + bl + in[n] @ Wr^T )
// Quarter-wave q owns node n0+q (16 lanes x float4 = full 256B row).
// Padded slices -> maskless unroll-8 gather; pad contribution subtracted once.
// Combine is k-outer: per k, 2 LDS weight reads shared by all 4 nodes.

__global__ void __launch_bounds__(256) sage_kernel(
    const float* __restrict__ in, const int* __restrict__ beg_,
    const int* __restrict__ cnt_, const int* __restrict__ srclist,
    const float* __restrict__ Wl, const float* __restrict__ bl,
    const float* __restrict__ Wr, float* __restrict__ out,
    int N, int relu) {
    __shared__ float wtl[D * D];   // wtl[k*64 + f] = Wl[f][k]
    __shared__ float wtr[D * D];
    int tid = threadIdx.x;
    for (int idx = tid; idx < D * D; idx += 256) {
        int f = idx & 63, k = idx >> 6;
        wtl[k * D + f] = Wl[f * D + k];
        wtr[k * D + f] = Wr[f * D + k];
    }
    __syncthreads();

    int lane = tid & 63;
    int q    = lane >> 4;    // which node of the 4
    int fl   = lane & 15;    // float4 slice within the row
    float bias = bl[lane];
    int gwave   = blockIdx.x * 4 + (tid >> 6);
    int nwaves  = gridDim.x * 4;
    int ngroups = (N + 3) >> 2;

    for (int t = gwave; t < ngroups; t += nwaves) {
        int n0 = t * 4;
        int node = n0 + q;
        bool nv = node < N;
        int beg = nv ? beg_[node] : 0;
        int deg = nv ? cnt_[node] : 0;
        int pdeg = (deg + 7) & ~7;

        // root rows early (independent; hides gather latency)
        float x0 = (n0     < N) ? in[(size_t)(n0    ) * D + lane] : 0.f;
        float x1 = (n0 + 1 < N) ? in[(size_t)(n0 + 1) * D + lane] : 0.f;
        float x2 = (n0 + 2 < N) ? in[(size_t)(n0 + 2) * D + lane] : 0.f;
        float x3 = (n0 + 3 < N) ? in[(size_t)(n0 + 3) * D + lane] : 0.f;

        float ax = 0.f, ay = 0.f, az = 0.f, aw = 0.f;
        for (int j = 0; j < pdeg; j += 8) {
#pragma unroll
            for (int u = 0; u < 8; ++u) {
                int si = srclist[beg + j + u];
                const float4 v = *((const float4*)(in + (size_t)si * D) + fl);
                ax += v.x; ay += v.y; az += v.z; aw += v.w;
            }
        }
        if (pdeg > deg) {   // remove pad-slot contribution (pads replicate srclist[beg])
            int si0 = srclist[beg];
            const float4 v = *((const float4*)(in + (size_t)si0 * D) + fl);
            float pc = (float)(pdeg - deg);
            ax = fmaf(-pc, v.x, ax); ay = fmaf(-pc, v.y, ay);
            az = fmaf(-pc, v.z, az); aw = fmaf(-pc, v.w, aw);
        }
        float scale = (deg > 0) ? 1.0f / (float)deg : 0.0f;
        ax *= scale; ay *= scale; az *= scale; aw *= scale;

        float c0 = bias, c1 = bias, c2 = bias, c3 = bias;
#pragma unroll
        for (int kk = 0; kk < 16; ++kk) {
#pragma unroll
            for (int kc = 0; kc < 4; ++kc) {
                int k = 4 * kk + kc;
                float wl = wtl[k * D + lane];
                float wr = wtr[k * D + lane];
                float s0 = (kc == 0) ? ax : (kc == 1) ? ay : (kc == 2) ? az : aw;
                c0 += lane_bcast(s0, kk)      * wl;
                c1 += lane_bcast(s0, 16 + kk) * wl;
                c2 += lane_bcast(s0, 32 + kk) * wl;
                c3 += lane_bcast(s0, 48 + kk) * wl;
                c0 += lane_bcast(x0, k) * wr;
                c1 += lane_bcast(x1, k) * wr;
                c2 += lane_bcast(x2, k) * wr;
                c3 += lane_bcast(x3, k) * wr;
            }
        }
        if (relu) {
            c0 = fmaxf(c0, 0.f); c1 = fmaxf(c1, 0.f);
            c2 = fmaxf(c2, 0.f); c3 = fmaxf(c3, 0.f);
        }
        size_t r0 = (size_t)n0 * D + lane;
        out[r0] = c0;
        if (n0 + 1 < N) out[r0 + D]     = c1;
        if (n0 + 2 < N) out[r0 + 2 * D] = c2;
        if (n0 + 3 < N) out[r0 + 3 * D] = c3;
    }
}

extern "C" void kernel_launch(void* const* d_in, const int* in_sizes, int n_in,
                              void* d_out, int out_size, void* d_ws, size_t ws_size,
                              hipStream_t stream) {
    const float* x   = (const float*)d_in[0];
    const int*   ei  = (const int*)d_in[1];
    const float* W1l = (const float*)d_in[2];
    const float* b1l = (const float*)d_in[3];
    const float* W1r = (const float*)d_in[4];
    const float* W2l = (const float*)d_in[5];
    const float* b2l = (const float*)d_in[6];
    const float* W2r = (const float*)d_in[7];
    float* out = (float*)d_out;

    int N = in_sizes[0] / D;   // 100000
    int E = in_sizes[1] / 2;   // 1000000

    char* ws = (char*)d_ws;
    // h occupies [0, N*D*4); head/edge2 alias it during the build phase
    // (dead before sage1 writes h). N*4 is 8B-aligned for int2.
    float* h       = (float*)ws;
    int*   head    = (int*)ws;                            // N ints (alias h)
    int2*  edge2   = (int2*)(ws + (size_t)N * 4);         // E int2 (alias h)
    int*   srclist = (int*)(ws + (size_t)N * D * 4);      // E + 8N + 64 ints
    int*   beg     = srclist + E + 8 * N + 64;            // N ints
    int*   cnt     = beg + N;                             // N ints
    int*   total   = cnt + N;                             // 1 int

    hipMemsetAsync(head, 0xFF, (size_t)N * 4, stream);            // head = -1
    hipMemsetAsync(cnt, 0, (size_t)(N + 1) * 4, stream);          // cnt + total = 0

    int eblocks = (E + 255) / 256;
    int nblocks = (N + 255) / 256;
    build_kernel<<<eblocks, 256, 0, stream>>>(ei, head, edge2, cnt, E);
    alloc_kernel<<<nblocks, 256, 0, stream>>>(cnt, beg, total, N);
    fill_kernel<<<nblocks, 256, 0, stream>>>(edge2, head, beg, cnt, srclist, N);

    // layer 1: h = relu(mean_agg(x)@W1l^T + b1l + x@W1r^T)
    sage_kernel<<<1280, 256, 0, stream>>>(x, beg, cnt, srclist, W1l, b1l, W1r, h, N, 1);
    // layer 2: out = mean_agg(h)@W2l^T + b2l + h@W2r^T
    sage_kernel<<<1280, 256, 0, stream>>>(h, beg, cnt, srclist, W2l, b2l, W2r, out, N, 0);
}

// Round 6
// 431.129 us; speedup vs baseline: 1.1185x; 1.1185x over previous
//
#include <hip/hip_runtime.h>

#define D 64

__device__ __forceinline__ float lane_bcast(float v, int k) {
    return __int_as_float(__builtin_amdgcn_readlane(__float_as_int(v), k));
}

__device__ __forceinline__ ushort f2bf(float f) {     // fp32 -> bf16, RNE
    unsigned u = __float_as_uint(f);
    u += 0x7fffu + ((u >> 16) & 1u);
    return (ushort)(u >> 16);
}

// ---------------- cast x to bf16 rows ----------------
__global__ void cast_kernel(const float* __restrict__ x, ushort* __restrict__ xh, int n4) {
    int i = blockIdx.x * blockDim.x + threadIdx.x;
    if (i >= n4) return;
    float4 v = ((const float4*)x)[i];
    ushort4 r;
    r.x = f2bf(v.x); r.y = f2bf(v.y); r.z = f2bf(v.z); r.w = f2bf(v.w);
    ((ushort4*)xh)[i] = r;
}

// ---------------- build: linked list with {src,next} packed + degree ----------------
__global__ void build_kernel(const int* __restrict__ ei, int* __restrict__ head,
                             int2* __restrict__ edge2, int* __restrict__ cnt, int E) {
    int e = blockIdx.x * blockDim.x + threadIdx.x;
    if (e < E) {
        int src = ei[e];
        int dst = ei[E + e];
        int prev = atomicExch(&head[dst], e);
        edge2[e] = make_int2(src, prev);
        atomicAdd(&cnt[dst], 1);
    }
}

// pure wave-scan bump allocator (no chain walk)
__global__ void alloc_kernel(const int* __restrict__ cnt, int* __restrict__ beg,
                             int* __restrict__ total, int N) {
    int i = blockIdx.x * blockDim.x + threadIdx.x;
    int lane = threadIdx.x & 63;
    int c = (i < N) ? cnt[i] : 0;
    int p = c;
#pragma unroll
    for (int o = 1; o < 64; o <<= 1) {
        int u = __shfl_up(p, o, 64);
        if (lane >= o) p += u;
    }
    int wavetot = __shfl(p, 63, 64);
    int base = 0;
    if (lane == 63) base = atomicAdd(total, wavetot);
    base = __shfl(base, 63, 64);
    if (i < N) beg[i] = base + p - c;
}

// thread per node: walk chain (one 8B read per hop), sequential slice writes
__global__ void fill_kernel(const int2* __restrict__ edge2, const int* __restrict__ head,
                            const int* __restrict__ beg_, int* __restrict__ srclist, int N) {
    int i = blockIdx.x * blockDim.x + threadIdx.x;
    if (i >= N) return;
    int e = head[i];
    if (e < 0) return;
    int p = beg_[i];
    for (;;) {
        int2 sn = edge2[e];
        srclist[p++] = sn.x;
        e = sn.y;
        if (e < 0) break;
    }
}

// ---------------- fused SAGE layer (bf16 gather, fp32 math) ----------------
// out[n] = [relu]( mean_{s in N(n)} in[s] @ Wl^T + bl + root[n] @ Wr^T )
// Quarter-wave q owns node n0+q; its 16 lanes each hold 4 features (8B bf16 load).
// Round-4 proven shape: clamped unroll-4 gather + q2-outer combine (low VGPR).

__global__ void __launch_bounds__(256) sage_kernel(
    const ushort* __restrict__ inh,      // bf16 rows [N][64]
    const float* __restrict__ root_f32,  // fp32 roots if non-null, else roots from inh
    const int* __restrict__ beg_, const int* __restrict__ cnt_,
    const int* __restrict__ srclist,
    const float* __restrict__ Wl, const float* __restrict__ bl,
    const float* __restrict__ Wr,
    float* __restrict__ out_f32,         // fp32 output (layer 2) or null
    ushort* __restrict__ out_bf,         // bf16 output (layer 1) or null
    int N, int relu) {
    __shared__ float wtl[D * D];   // wtl[k*64 + f] = Wl[f][k]
    __shared__ float wtr[D * D];
    int tid = threadIdx.x;
    for (int idx = tid; idx < D * D; idx += 256) {
        int f = idx & 63, k = idx >> 6;
        wtl[k * D + f] = Wl[f * D + k];
        wtr[k * D + f] = Wr[f * D + k];
    }
    __syncthreads();

    int lane = tid & 63;
    int q    = lane >> 4;    // which node of the 4
    int fl   = lane & 15;    // 4-feature slice within the row
    float bias = bl[lane];
    int gwave   = blockIdx.x * 4 + (tid >> 6);
    int nwaves  = gridDim.x * 4;
    int ngroups = (N + 3) >> 2;

    for (int t = gwave; t < ngroups; t += nwaves) {
        int n0 = t * 4;
        int node = n0 + q;
        bool nv = node < N;
        int beg = nv ? beg_[node] : 0;
        int deg = nv ? cnt_[node] : 0;

        // root rows (coalesced)
        float x0, x1, x2, x3;
        if (root_f32) {
            x0 = (n0     < N) ? root_f32[(size_t)(n0    ) * D + lane] : 0.f;
            x1 = (n0 + 1 < N) ? root_f32[(size_t)(n0 + 1) * D + lane] : 0.f;
            x2 = (n0 + 2 < N) ? root_f32[(size_t)(n0 + 2) * D + lane] : 0.f;
            x3 = (n0 + 3 < N) ? root_f32[(size_t)(n0 + 3) * D + lane] : 0.f;
        } else {
            x0 = (n0     < N) ? __int_as_float((unsigned)inh[(size_t)(n0    ) * D + lane] << 16) : 0.f;
            x1 = (n0 + 1 < N) ? __int_as_float((unsigned)inh[(size_t)(n0 + 1) * D + lane] << 16) : 0.f;
            x2 = (n0 + 2 < N) ? __int_as_float((unsigned)inh[(size_t)(n0 + 2) * D + lane] << 16) : 0.f;
            x3 = (n0 + 3 < N) ? __int_as_float((unsigned)inh[(size_t)(n0 + 3) * D + lane] << 16) : 0.f;
        }

        float ax = 0.f, ay = 0.f, az = 0.f, aw = 0.f;
        for (int j = 0; j < deg; j += 4) {
#pragma unroll
            for (int u = 0; u < 4; ++u) {
                int jj = j + u;
                int idx = beg + ((jj < deg) ? jj : (deg - 1));
                int si = srclist[idx];                       // wave-quarter uniform
                const uint2 v = *((const uint2*)(inh + (size_t)si * D) + fl);
                float m = (jj < deg) ? 1.f : 0.f;
                ax = fmaf(m, __int_as_float(v.x << 16), ax);
                ay = fmaf(m, __int_as_float(v.x & 0xffff0000u), ay);
                az = fmaf(m, __int_as_float(v.y << 16), az);
                aw = fmaf(m, __int_as_float(v.y & 0xffff0000u), aw);
            }
        }
        float scale = (deg > 0) ? 1.0f / (float)deg : 0.0f;
        ax *= scale; ay *= scale; az *= scale; aw *= scale;

#pragma unroll
        for (int q2 = 0; q2 < 4; ++q2) {
            int n2 = n0 + q2;
            if (n2 >= N) break;
            float xr = (q2 == 0) ? x0 : (q2 == 1) ? x1 : (q2 == 2) ? x2 : x3;
            float c = bias;
#pragma unroll
            for (int j = 0; j < 16; ++j) {
                int sl = q2 * 16 + j;   // lane holding features 4j..4j+3 of node q2's agg
                c += lane_bcast(ax, sl) * wtl[(4 * j + 0) * D + lane]
                   + lane_bcast(ay, sl) * wtl[(4 * j + 1) * D + lane]
                   + lane_bcast(az, sl) * wtl[(4 * j + 2) * D + lane]
                   + lane_bcast(aw, sl) * wtl[(4 * j + 3) * D + lane];
                c += lane_bcast(xr, 4 * j + 0) * wtr[(4 * j + 0) * D + lane]
                   + lane_bcast(xr, 4 * j + 1) * wtr[(4 * j + 1) * D + lane]
                   + lane_bcast(xr, 4 * j + 2) * wtr[(4 * j + 2) * D + lane]
                   + lane_bcast(xr, 4 * j + 3) * wtr[(4 * j + 3) * D + lane];
            }
            if (relu) c = fmaxf(c, 0.f);
            size_t r2 = (size_t)n2 * D + lane;
            if (out_bf) out_bf[r2] = f2bf(c);
            else        out_f32[r2] = c;
        }
    }
}

extern "C" void kernel_launch(void* const* d_in, const int* in_sizes, int n_in,
                              void* d_out, int out_size, void* d_ws, size_t ws_size,
                              hipStream_t stream) {
    const float* x   = (const float*)d_in[0];
    const int*   ei  = (const int*)d_in[1];
    const float* W1l = (const float*)d_in[2];
    const float* b1l = (const float*)d_in[3];
    const float* W1r = (const float*)d_in[4];
    const float* W2l = (const float*)d_in[5];
    const float* b2l = (const float*)d_in[6];
    const float* W2r = (const float*)d_in[7];
    float* out = (float*)d_out;

    int N = in_sizes[0] / D;   // 100000
    int E = in_sizes[1] / 2;   // 1000000

    char* ws = (char*)d_ws;
    // Layout (bytes):
    //   [0, N*D*2)            xh  : bf16 x rows
    //   [N*D*2, 2*N*D*2)      hh  : bf16 h rows; build-phase head/edge2 alias here
    //                               (dead before sage1 writes hh)
    //   then srclist, beg, cnt, total
    ushort* xh = (ushort*)ws;
    ushort* hh = xh + (size_t)N * D;
    int*   head  = (int*)hh;                              // N ints (alias hh)
    int2*  edge2 = (int2*)((char*)hh + (size_t)N * 4);    // E int2 (alias hh; 8B aligned)
    int*   srclist = (int*)(ws + (size_t)2 * N * D * 2);  // E ints
    int*   beg   = srclist + E;                           // N ints
    int*   cnt   = beg + N;                               // N ints
    int*   total = cnt + N;                               // 1 int

    hipMemsetAsync(head, 0xFF, (size_t)N * 4, stream);    // head = -1
    hipMemsetAsync(cnt, 0, (size_t)(N + 1) * 4, stream);  // cnt + total = 0

    int n4 = N * D / 4;
    cast_kernel<<<(n4 + 255) / 256, 256, 0, stream>>>(x, xh, n4);

    int eblocks = (E + 255) / 256;
    int nblocks = (N + 255) / 256;
    build_kernel<<<eblocks, 256, 0, stream>>>(ei, head, edge2, cnt, E);
    alloc_kernel<<<nblocks, 256, 0, stream>>>(cnt, beg, total, N);
    fill_kernel<<<nblocks, 256, 0, stream>>>(edge2, head, beg, srclist, N);

    // layer 1: hh(bf16) = relu(mean_agg(xh)@W1l^T + b1l + x@W1r^T)   (root in fp32)
    sage_kernel<<<1280, 256, 0, stream>>>(xh, x, beg, cnt, srclist,
                                          W1l, b1l, W1r, nullptr, hh, N, 1);
    // layer 2: out(fp32) = mean_agg(hh)@W2l^T + b2l + hh@W2r^T
    sage_kernel<<<1280, 256, 0, stream>>>(hh, nullptr, beg, cnt, srclist,
                                          W2l, b2l, W2r, out, nullptr, N, 0);
}

// Round 7
// 322.364 us; speedup vs baseline: 1.4959x; 1.3374x over previous
//
#include <hip/hip_runtime.h>

#define D 64

typedef __attribute__((ext_vector_type(8))) short short8;   // 8 bf16 = 4 VGPRs
typedef __attribute__((ext_vector_type(4))) float floatx4;  // MFMA C/D

__device__ __forceinline__ ushort f2bf(float f) {     // fp32 -> bf16, RNE
    unsigned u = __float_as_uint(f);
    u += 0x7fffu + ((u >> 16) & 1u);
    return (ushort)(u >> 16);
}
__device__ __forceinline__ float bf2f(ushort h) {
    return __int_as_float(((unsigned)h) << 16);
}

// ---------------- cast x to bf16 rows ----------------
__global__ void cast_kernel(const float* __restrict__ x, ushort* __restrict__ xh, int n4) {
    int i = blockIdx.x * blockDim.x + threadIdx.x;
    if (i >= n4) return;
    float4 v = ((const float4*)x)[i];
    ushort4 r;
    r.x = f2bf(v.x); r.y = f2bf(v.y); r.z = f2bf(v.z); r.w = f2bf(v.w);
    ((ushort4*)xh)[i] = r;
}

// ---------------- build: linked list with {src,next} packed + degree ----------------
__global__ void build_kernel(const int* __restrict__ ei, int* __restrict__ head,
                             int2* __restrict__ edge2, int* __restrict__ cnt, int E) {
    int e = blockIdx.x * blockDim.x + threadIdx.x;
    if (e < E) {
        int src = ei[e];
        int dst = ei[E + e];
        int prev = atomicExch(&head[dst], e);
        edge2[e] = make_int2(src, prev);
        atomicAdd(&cnt[dst], 1);
    }
}

// pure wave-scan bump allocator
__global__ void alloc_kernel(const int* __restrict__ cnt, int* __restrict__ beg,
                             int* __restrict__ total, int N) {
    int i = blockIdx.x * blockDim.x + threadIdx.x;
    int lane = threadIdx.x & 63;
    int c = (i < N) ? cnt[i] : 0;
    int p = c;
#pragma unroll
    for (int o = 1; o < 64; o <<= 1) {
        int u = __shfl_up(p, o, 64);
        if (lane >= o) p += u;
    }
    int wavetot = __shfl(p, 63, 64);
    int base = 0;
    if (lane == 63) base = atomicAdd(total, wavetot);
    base = __shfl(base, 63, 64);
    if (i < N) beg[i] = base + p - c;
}

// thread per node: walk chain (one 8B read per hop), sequential slice writes
__global__ void fill_kernel(const int2* __restrict__ edge2, const int* __restrict__ head,
                            const int* __restrict__ beg_, int* __restrict__ srclist, int N) {
    int i = blockIdx.x * blockDim.x + threadIdx.x;
    if (i >= N) return;
    int e = head[i];
    if (e < 0) return;
    int p = beg_[i];
    for (;;) {
        int2 sn = edge2[e];
        srclist[p++] = sn.x;
        e = sn.y;
        if (e < 0) break;
    }
}

// ---------------- fused SAGE layer: bf16 gather + MFMA combine ----------------
// 16 nodes per wave. Lane L = (q=L>>4, m=L&15):
//   gather: lane accumulates features [q*8, q*8+8) and [32+q*8, ...) of node base+m
//           (exactly its MFMA A-fragment elements), 2x 16B bf16 loads per neighbor.
//   combine: D(16x16) tiles via mfma_f32_16x16x32_bf16, B-frags (Wl^T / Wr^T bf16)
//            prebuilt in LDS per block; C/D layout col=lane&15, row=q*4+reg.

__global__ void __launch_bounds__(256, 4) sage_kernel(
    const ushort* __restrict__ inh,      // bf16 rows [N][64]
    const int* __restrict__ beg_, const int* __restrict__ cnt_,
    const int* __restrict__ srclist,
    const float* __restrict__ Wl, const float* __restrict__ bl,
    const float* __restrict__ Wr,
    float* __restrict__ out_f32,         // fp32 out (layer 2) or null
    ushort* __restrict__ out_bf,         // bf16 out (layer 1) or null
    int N, int relu) {
    __shared__ short8 fL[8][64];   // [c*2+s][lane]: B-frag of Wl^T, col-tile c, k-step s
    __shared__ short8 fR[8][64];
    int tid = threadIdx.x;
    int lane = tid & 63;
    {
        int c = tid >> 6;          // this wave builds col-tile c's fragments
        int n = lane & 15;
        int q = lane >> 4;
#pragma unroll
        for (int s = 0; s < 2; ++s) {
            const float* pl = Wl + (c * 16 + n) * D + s * 32 + q * 8;
            const float* pr = Wr + (c * 16 + n) * D + s * 32 + q * 8;
            short8 vl, vr;
#pragma unroll
            for (int j = 0; j < 8; ++j) {
                vl[j] = (short)f2bf(pl[j]);
                vr[j] = (short)f2bf(pr[j]);
            }
            fL[c * 2 + s][lane] = vl;
            fR[c * 2 + s][lane] = vr;
        }
    }
    __syncthreads();

    int m = lane & 15;
    int q = lane >> 4;
    float b0 = bl[m], b1 = bl[16 + m], b2 = bl[32 + m], b3 = bl[48 + m];
    int gwave   = blockIdx.x * 4 + (tid >> 6);
    int nwaves  = gridDim.x * 4;
    int ngroups = (N + 15) >> 4;

    for (int g = gwave; g < ngroups; g += nwaves) {
        int base = g * 16;
        int node = base + m;
        bool nv = node < N;
        int beg = nv ? beg_[node] : 0;   // 4 lanes per node share the address
        int deg = nv ? cnt_[node] : 0;

        // wave-max degree (deg depends only on m; xor over bits 0..3 covers all 16)
        int md = deg;
        md = max(md, __shfl_xor(md, 1, 64));
        md = max(md, __shfl_xor(md, 2, 64));
        md = max(md, __shfl_xor(md, 4, 64));
        md = max(md, __shfl_xor(md, 8, 64));

        float f0[8], f1[8];
#pragma unroll
        for (int u = 0; u < 8; ++u) { f0[u] = 0.f; f1[u] = 0.f; }

#pragma unroll 2
        for (int j = 0; j < md; ++j) {
            int idx = beg + ((j < deg) ? j : 0);
            int si = srclist[idx];
            const ushort* rp = inh + (size_t)si * D;
            short8 lo = *(const short8*)(rp + q * 8);        // features q*8..+7
            short8 hi = *(const short8*)(rp + 32 + q * 8);   // features 32+q*8..+7
            float msk = (j < deg) ? 1.f : 0.f;
#pragma unroll
            for (int u = 0; u < 8; ++u) {
                f0[u] = fmaf(msk, bf2f((ushort)lo[u]), f0[u]);
                f1[u] = fmaf(msk, bf2f((ushort)hi[u]), f1[u]);
            }
        }

        float scale = (deg > 0) ? 1.0f / (float)deg : 0.0f;
        short8 a0, a1;
#pragma unroll
        for (int u = 0; u < 8; ++u) {
            a0[u] = (short)f2bf(f0[u] * scale);
            a1[u] = (short)f2bf(f1[u] * scale);
        }

        // root rows load directly as A-fragments
        const ushort* rr = inh + (size_t)(nv ? node : 0) * D;
        short8 r0 = *(const short8*)(rr + q * 8);
        short8 r1 = *(const short8*)(rr + 32 + q * 8);

#pragma unroll
        for (int c = 0; c < 4; ++c) {
            float bc = (c == 0) ? b0 : (c == 1) ? b1 : (c == 2) ? b2 : b3;
            floatx4 acc = {bc, bc, bc, bc};
            acc = __builtin_amdgcn_mfma_f32_16x16x32_bf16(a0, fL[c * 2 + 0][lane], acc, 0, 0, 0);
            acc = __builtin_amdgcn_mfma_f32_16x16x32_bf16(a1, fL[c * 2 + 1][lane], acc, 0, 0, 0);
            acc = __builtin_amdgcn_mfma_f32_16x16x32_bf16(r0, fR[c * 2 + 0][lane], acc, 0, 0, 0);
            acc = __builtin_amdgcn_mfma_f32_16x16x32_bf16(r1, fR[c * 2 + 1][lane], acc, 0, 0, 0);
#pragma unroll
            for (int r = 0; r < 4; ++r) {
                float v = acc[r];
                if (relu) v = fmaxf(v, 0.f);
                int onode = base + q * 4 + r;    // D row = q*4 + reg
                if (onode < N) {
                    size_t off = (size_t)onode * D + c * 16 + m;   // D col = lane&15
                    if (out_bf) out_bf[off] = f2bf(v);
                    else        out_f32[off] = v;
                }
            }
        }
    }
}

extern "C" void kernel_launch(void* const* d_in, const int* in_sizes, int n_in,
                              void* d_out, int out_size, void* d_ws, size_t ws_size,
                              hipStream_t stream) {
    const float* x   = (const float*)d_in[0];
    const int*   ei  = (const int*)d_in[1];
    const float* W1l = (const float*)d_in[2];
    const float* b1l = (const float*)d_in[3];
    const float* W1r = (const float*)d_in[4];
    const float* W2l = (const float*)d_in[5];
    const float* b2l = (const float*)d_in[6];
    const float* W2r = (const float*)d_in[7];
    float* out = (float*)d_out;

    int N = in_sizes[0] / D;   // 100000
    int E = in_sizes[1] / 2;   // 1000000

    char* ws = (char*)d_ws;
    // Layout (bytes):
    //   [0, N*D*2)         xh : bf16 x rows
    //   [N*D*2, 2*N*D*2)   hh : bf16 h rows; build-phase head/edge2 alias here
    //   then srclist (+slack), beg, cnt, total
    ushort* xh = (ushort*)ws;
    ushort* hh = xh + (size_t)N * D;
    int*   head  = (int*)hh;                              // N ints (alias hh)
    int2*  edge2 = (int2*)((char*)hh + (size_t)N * 4);    // E int2 (alias hh)
    int*   srclist = (int*)(ws + (size_t)2 * N * D * 2);  // E ints + 64 slack
    int*   beg   = srclist + E + 64;                      // N ints
    int*   cnt   = beg + N;                               // N ints
    int*   total = cnt + N;                               // 1 int

    hipMemsetAsync(head, 0xFF, (size_t)N * 4, stream);    // head = -1
    hipMemsetAsync(cnt, 0, (size_t)(N + 1) * 4, stream);  // cnt + total = 0

    int n4 = N * D / 4;
    cast_kernel<<<(n4 + 255) / 256, 256, 0, stream>>>(x, xh, n4);

    int eblocks = (E + 255) / 256;
    int nblocks = (N + 255) / 256;
    build_kernel<<<eblocks, 256, 0, stream>>>(ei, head, edge2, cnt, E);
    alloc_kernel<<<nblocks, 256, 0, stream>>>(cnt, beg, total, N);
    fill_kernel<<<nblocks, 256, 0, stream>>>(edge2, head, beg, srclist, N);

    int ngroups = (N + 15) / 16;              // 6250
    int sblocks = (ngroups + 3) / 4;          // 1 group per wave
    // layer 1: hh(bf16) = relu(mean_agg(xh)@W1l^T + b1l + xh@W1r^T)
    sage_kernel<<<sblocks, 256, 0, stream>>>(xh, beg, cnt, srclist,
                                             W1l, b1l, W1r, nullptr, hh, N, 1);
    // layer 2: out(fp32) = mean_agg(hh)@W2l^T + b2l + hh@W2r^T
    sage_kernel<<<sblocks, 256, 0, stream>>>(hh, beg, cnt, srclist,
                                             W2l, b2l, W2r, out, nullptr, N, 0);
}

// Round 8
// 285.221 us; speedup vs baseline: 1.6908x; 1.1302x over previous
//
#include <hip/hip_runtime.h>

#define D 64

typedef __attribute__((ext_vector_type(8))) short short8;   // 8 bf16 = 4 VGPRs
typedef __attribute__((ext_vector_type(4))) float floatx4;  // MFMA C/D

__device__ __forceinline__ ushort f2bf(float f) {     // fp32 -> bf16, RNE
    unsigned u = __float_as_uint(f);
    u += 0x7fffu + ((u >> 16) & 1u);
    return (ushort)(u >> 16);
}
__device__ __forceinline__ float bf2f(ushort h) {
    return __int_as_float(((unsigned)h) << 16);
}

// ---------------- cast x to bf16 rows ----------------
__global__ void cast_kernel(const float* __restrict__ x, ushort* __restrict__ xh, int n4) {
    int i = blockIdx.x * blockDim.x + threadIdx.x;
    if (i >= n4) return;
    float4 v = ((const float4*)x)[i];
    ushort4 r;
    r.x = f2bf(v.x); r.y = f2bf(v.y); r.z = f2bf(v.z); r.w = f2bf(v.w);
    ((ushort4*)xh)[i] = r;
}

// ---------------- build: linked list, exch-only (1M atomics, 4B coalesced next) ----
__global__ void build_kernel(const int* __restrict__ ei, int* __restrict__ head,
                             int* __restrict__ next, int E) {
    int e = blockIdx.x * blockDim.x + threadIdx.x;
    if (e < E) next[e] = atomicExch(&head[ei[E + e]], e);
}

// ---------------- alloc+fill fused ----------------
// thread per node: (1) walk chain counting (dense 4B next reads),
// (2) wave-scan bump-allocate, (3) re-walk (warm) writing contiguous srclist slice.
__global__ void alloc_fill_kernel(const int* __restrict__ ei, const int* __restrict__ head,
                                  const int* __restrict__ next,
                                  int* __restrict__ beg_out, int* __restrict__ cnt_out,
                                  int* __restrict__ srclist, int* __restrict__ total, int N) {
    int i = blockIdx.x * blockDim.x + threadIdx.x;
    int lane = threadIdx.x & 63;
    int h = (i < N) ? head[i] : -1;
    int c = 0;
    for (int e = h; e >= 0; e = next[e]) ++c;
    int p = c;
#pragma unroll
    for (int o = 1; o < 64; o <<= 1) {
        int u = __shfl_up(p, o, 64);
        if (lane >= o) p += u;
    }
    int wavetot = __shfl(p, 63, 64);
    int base = 0;
    if (lane == 63) base = atomicAdd(total, wavetot);
    base = __shfl(base, 63, 64);
    int b = base + p - c;
    if (i < N) { beg_out[i] = b; cnt_out[i] = c; }
    int ptr = b;
    for (int e = h; e >= 0; e = next[e]) srclist[ptr++] = ei[e];
}

// ---------------- fused SAGE layer: bf16 gather + MFMA combine ----------------
// 16 nodes per wave. Lane L = (q=L>>4, m=L&15):
//   gather: lane accumulates features [q*8, q*8+8) and [32+q*8, ...) of node base+m
//           (exactly its MFMA A-fragment elements), 2x 16B bf16 loads per neighbor.
//   combine: D(16x16) tiles via mfma_f32_16x16x32_bf16, B-frags (Wl^T / Wr^T bf16)
//            prebuilt in LDS per block; C/D layout col=lane&15, row=q*4+reg.

__global__ void __launch_bounds__(256, 4) sage_kernel(
    const ushort* __restrict__ inh,      // bf16 rows [N][64]
    const int* __restrict__ beg_, const int* __restrict__ cnt_,
    const int* __restrict__ srclist,
    const float* __restrict__ Wl, const float* __restrict__ bl,
    const float* __restrict__ Wr,
    float* __restrict__ out_f32,         // fp32 out (layer 2) or null
    ushort* __restrict__ out_bf,         // bf16 out (layer 1) or null
    int N, int relu) {
    __shared__ short8 fL[8][64];   // [c*2+s][lane]: B-frag of Wl^T, col-tile c, k-step s
    __shared__ short8 fR[8][64];
    int tid = threadIdx.x;
    int lane = tid & 63;
    {
        int c = tid >> 6;          // this wave builds col-tile c's fragments
        int n = lane & 15;
        int q = lane >> 4;
#pragma unroll
        for (int s = 0; s < 2; ++s) {
            const float* pl = Wl + (c * 16 + n) * D + s * 32 + q * 8;
            const float* pr = Wr + (c * 16 + n) * D + s * 32 + q * 8;
            short8 vl, vr;
#pragma unroll
            for (int j = 0; j < 8; ++j) {
                vl[j] = (short)f2bf(pl[j]);
                vr[j] = (short)f2bf(pr[j]);
            }
            fL[c * 2 + s][lane] = vl;
            fR[c * 2 + s][lane] = vr;
        }
    }
    __syncthreads();

    int m = lane & 15;
    int q = lane >> 4;
    float b0 = bl[m], b1 = bl[16 + m], b2 = bl[32 + m], b3 = bl[48 + m];
    int gwave   = blockIdx.x * 4 + (tid >> 6);
    int nwaves  = gridDim.x * 4;
    int ngroups = (N + 15) >> 4;

    for (int g = gwave; g < ngroups; g += nwaves) {
        int base = g * 16;
        int node = base + m;
        bool nv = node < N;
        int beg = nv ? beg_[node] : 0;   // 4 lanes per node share the address
        int deg = nv ? cnt_[node] : 0;

        // wave-max degree (deg depends only on m; xor over bits 0..3 covers all 16)
        int md = deg;
        md = max(md, __shfl_xor(md, 1, 64));
        md = max(md, __shfl_xor(md, 2, 64));
        md = max(md, __shfl_xor(md, 4, 64));
        md = max(md, __shfl_xor(md, 8, 64));

        float f0[8], f1[8];
#pragma unroll
        for (int u = 0; u < 8; ++u) { f0[u] = 0.f; f1[u] = 0.f; }

#pragma unroll 2
        for (int j = 0; j < md; ++j) {
            int idx = beg + ((j < deg) ? j : 0);
            int si = srclist[idx];
            const ushort* rp = inh + (size_t)si * D;
            short8 lo = *(const short8*)(rp + q * 8);        // features q*8..+7
            short8 hi = *(const short8*)(rp + 32 + q * 8);   // features 32+q*8..+7
            float msk = (j < deg) ? 1.f : 0.f;
#pragma unroll
            for (int u = 0; u < 8; ++u) {
                f0[u] = fmaf(msk, bf2f((ushort)lo[u]), f0[u]);
                f1[u] = fmaf(msk, bf2f((ushort)hi[u]), f1[u]);
            }
        }

        float scale = (deg > 0) ? 1.0f / (float)deg : 0.0f;
        short8 a0, a1;
#pragma unroll
        for (int u = 0; u < 8; ++u) {
            a0[u] = (short)f2bf(f0[u] * scale);
            a1[u] = (short)f2bf(f1[u] * scale);
        }

        // root rows load directly as A-fragments
        const ushort* rr = inh + (size_t)(nv ? node : 0) * D;
        short8 r0 = *(const short8*)(rr + q * 8);
        short8 r1 = *(const short8*)(rr + 32 + q * 8);

#pragma unroll
        for (int c = 0; c < 4; ++c) {
            float bc = (c == 0) ? b0 : (c == 1) ? b1 : (c == 2) ? b2 : b3;
            floatx4 acc = {bc, bc, bc, bc};
            acc = __builtin_amdgcn_mfma_f32_16x16x32_bf16(a0, fL[c * 2 + 0][lane], acc, 0, 0, 0);
            acc = __builtin_amdgcn_mfma_f32_16x16x32_bf16(a1, fL[c * 2 + 1][lane], acc, 0, 0, 0);
            acc = __builtin_amdgcn_mfma_f32_16x16x32_bf16(r0, fR[c * 2 + 0][lane], acc, 0, 0, 0);
            acc = __builtin_amdgcn_mfma_f32_16x16x32_bf16(r1, fR[c * 2 + 1][lane], acc, 0, 0, 0);
#pragma unroll
            for (int r = 0; r < 4; ++r) {
                float v = acc[r];
                if (relu) v = fmaxf(v, 0.f);
                int onode = base + q * 4 + r;    // D row = q*4 + reg
                if (onode < N) {
                    size_t off = (size_t)onode * D + c * 16 + m;   // D col = lane&15
                    if (out_bf) out_bf[off] = f2bf(v);
                    else        out_f32[off] = v;
                }
            }
        }
    }
}

extern "C" void kernel_launch(void* const* d_in, const int* in_sizes, int n_in,
                              void* d_out, int out_size, void* d_ws, size_t ws_size,
                              hipStream_t stream) {
    const float* x   = (const float*)d_in[0];
    const int*   ei  = (const int*)d_in[1];
    const float* W1l = (const float*)d_in[2];
    const float* b1l = (const float*)d_in[3];
    const float* W1r = (const float*)d_in[4];
    const float* W2l = (const float*)d_in[5];
    const float* b2l = (const float*)d_in[6];
    const float* W2r = (const float*)d_in[7];
    float* out = (float*)d_out;

    int N = in_sizes[0] / D;   // 100000
    int E = in_sizes[1] / 2;   // 1000000

    char* ws = (char*)d_ws;
    // Layout (bytes):
    //   [0, N*D*2)         xh : bf16 x rows
    //   [N*D*2, 2*N*D*2)   hh : bf16 h rows; build-phase head/next alias here
    //                          (dead before sage1 writes hh)
    //   then srclist (+slack), beg, cnt, total
    ushort* xh = (ushort*)ws;
    ushort* hh = xh + (size_t)N * D;
    int*   head  = (int*)hh;                              // N ints (alias hh)
    int*   next  = head + N;                              // E ints (alias hh)
    int*   srclist = (int*)(ws + (size_t)2 * N * D * 2);  // E ints + 64 slack
    int*   beg   = srclist + E + 64;                      // N ints
    int*   cnt   = beg + N;                               // N ints
    int*   total = cnt + N;                               // 1 int

    hipMemsetAsync(head, 0xFF, (size_t)N * 4, stream);    // head = -1
    hipMemsetAsync(total, 0, 4, stream);

    int n4 = N * D / 4;
    cast_kernel<<<(n4 + 255) / 256, 256, 0, stream>>>(x, xh, n4);

    int eblocks = (E + 255) / 256;
    int nblocks = (N + 255) / 256;
    build_kernel<<<eblocks, 256, 0, stream>>>(ei, head, next, E);
    alloc_fill_kernel<<<nblocks, 256, 0, stream>>>(ei, head, next, beg, cnt,
                                                   srclist, total, N);

    int ngroups = (N + 15) / 16;              // 6250
    int sblocks = (ngroups + 3) / 4;          // 1 group per wave
    // layer 1: hh(bf16) = relu(mean_agg(xh)@W1l^T + b1l + xh@W1r^T)
    sage_kernel<<<sblocks, 256, 0, stream>>>(xh, beg, cnt, srclist,
                                             W1l, b1l, W1r, nullptr, hh, N, 1);
    // layer 2: out(fp32) = mean_agg(hh)@W2l^T + b2l + hh@W2r^T
    sage_kernel<<<sblocks, 256, 0, stream>>>(hh, beg, cnt, srclist,
                                             W2l, b2l, W2r, out, nullptr, N, 0);
}

// Round 9
// 277.739 us; speedup vs baseline: 1.7363x; 1.0269x over previous
//
#include <hip/hip_runtime.h>

#define D 64

typedef __attribute__((ext_vector_type(8))) short short8;   // 8 bf16 = 4 VGPRs
typedef __attribute__((ext_vector_type(4))) float floatx4;  // MFMA C/D

__device__ __forceinline__ ushort f2bf(float f) {     // fp32 -> bf16, RNE
    unsigned u = __float_as_uint(f);
    u += 0x7fffu + ((u >> 16) & 1u);
    return (ushort)(u >> 16);
}
__device__ __forceinline__ float bf2f(ushort h) {
    return __int_as_float(((unsigned)h) << 16);
}

// ---------------- cast x to bf16 rows + init head/hist/total ----------------
__global__ void cast_kernel(const float* __restrict__ x, ushort* __restrict__ xh,
                            int* __restrict__ head, int* __restrict__ hist,
                            int* __restrict__ total, int n4, int N) {
    int i = blockIdx.x * blockDim.x + threadIdx.x;
    if (i < N) head[i] = -1;
    if (i < 64) hist[i] = 0;
    if (i == 0) *total = 0;
    if (i >= n4) return;
    float4 v = ((const float4*)x)[i];
    ushort4 r;
    r.x = f2bf(v.x); r.y = f2bf(v.y); r.z = f2bf(v.z); r.w = f2bf(v.w);
    ((ushort4*)xh)[i] = r;
}

// ---------------- build: linked list, exch-only ----------------
__global__ void build_kernel(const int* __restrict__ ei, int* __restrict__ head,
                             int* __restrict__ next, int E) {
    int e = blockIdx.x * blockDim.x + threadIdx.x;
    if (e < E) next[e] = atomicExch(&head[ei[E + e]], e);
}

// ---------------- alloc+fill (+ degree histogram) ----------------
__global__ void alloc_fill_kernel(const int* __restrict__ ei, const int* __restrict__ head,
                                  const int* __restrict__ next,
                                  int* __restrict__ beg_out, int* __restrict__ cnt_out,
                                  int* __restrict__ srclist, int* __restrict__ total,
                                  int* __restrict__ hist, int N) {
    __shared__ int lh[64];
    int tid = threadIdx.x;
    if (tid < 64) lh[tid] = 0;
    __syncthreads();
    int i = blockIdx.x * blockDim.x + tid;
    int lane = tid & 63;
    int h = (i < N) ? head[i] : -1;
    int c = 0;
    for (int e = h; e >= 0; e = next[e]) ++c;
    if (i < N) atomicAdd(&lh[c < 63 ? c : 63], 1);
    int p = c;
#pragma unroll
    for (int o = 1; o < 64; o <<= 1) {
        int u = __shfl_up(p, o, 64);
        if (lane >= o) p += u;
    }
    int wavetot = __shfl(p, 63, 64);
    int base = 0;
    if (lane == 63) base = atomicAdd(total, wavetot);
    base = __shfl(base, 63, 64);
    int b = base + p - c;
    if (i < N) { beg_out[i] = b; cnt_out[i] = c; }
    int ptr = b;
    for (int e = h; e >= 0; e = next[e]) srclist[ptr++] = ei[e];
    __syncthreads();
    if (tid < 64 && lh[tid] > 0) atomicAdd(&hist[tid], lh[tid]);
}

// ---------------- exclusive scan of 64 degree bins (1 wave) ----------------
__global__ void binscan_kernel(const int* __restrict__ hist, int* __restrict__ bincur) {
    int lane = threadIdx.x & 63;
    int c = hist[lane];
    int p = c;
#pragma unroll
    for (int o = 1; o < 64; o <<= 1) {
        int u = __shfl_up(p, o, 64);
        if (lane >= o) p += u;
    }
    bincur[lane] = p - c;   // exclusive prefix
}

// ---------------- scatter nodes into degree-sorted perm ----------------
__global__ void scatter_kernel(const int* __restrict__ cnt, int* __restrict__ bincur,
                               int* __restrict__ perm, int N) {
    __shared__ int lh[64];
    __shared__ int lbase[64];
    int tid = threadIdx.x;
    if (tid < 64) lh[tid] = 0;
    __syncthreads();
    int i = blockIdx.x * blockDim.x + tid;
    int bin = 0, slot = 0;
    if (i < N) {
        int c = cnt[i];
        bin = c < 63 ? c : 63;
        slot = atomicAdd(&lh[bin], 1);
    }
    __syncthreads();
    if (tid < 64 && lh[tid] > 0) lbase[tid] = atomicAdd(&bincur[tid], lh[tid]);
    __syncthreads();
    if (i < N) perm[lbase[bin] + slot] = i;
}

// ---------------- fused SAGE layer: bf16 gather + MFMA combine ----------------
// 16 nodes per wave via degree-sorted perm (uniform degree -> md ~= deg).
// Lane L = (q=L>>4, m=L&15): gather accumulates the lane's MFMA A-frag features
// of node perm[base+m]; combine = 16 mfma_f32_16x16x32_bf16 with LDS B-frags.

__global__ void __launch_bounds__(256, 4) sage_kernel(
    const ushort* __restrict__ inh,      // bf16 rows [N][64]
    const int* __restrict__ perm,
    const int* __restrict__ beg_, const int* __restrict__ cnt_,
    const int* __restrict__ srclist,
    const float* __restrict__ Wl, const float* __restrict__ bl,
    const float* __restrict__ Wr,
    float* __restrict__ out_f32,         // fp32 out (layer 2) or null
    ushort* __restrict__ out_bf,         // bf16 out (layer 1) or null
    int N, int relu) {
    __shared__ short8 fL[8][64];   // [c*2+s][lane]: B-frag of Wl^T, col-tile c, k-step s
    __shared__ short8 fR[8][64];
    int tid = threadIdx.x;
    int lane = tid & 63;
    {
        int c = tid >> 6;
        int n = lane & 15;
        int q = lane >> 4;
#pragma unroll
        for (int s = 0; s < 2; ++s) {
            const float* pl = Wl + (c * 16 + n) * D + s * 32 + q * 8;
            const float* pr = Wr + (c * 16 + n) * D + s * 32 + q * 8;
            short8 vl, vr;
#pragma unroll
            for (int j = 0; j < 8; ++j) {
                vl[j] = (short)f2bf(pl[j]);
                vr[j] = (short)f2bf(pr[j]);
            }
            fL[c * 2 + s][lane] = vl;
            fR[c * 2 + s][lane] = vr;
        }
    }
    __syncthreads();

    int m = lane & 15;
    int q = lane >> 4;
    float b0 = bl[m], b1 = bl[16 + m], b2 = bl[32 + m], b3 = bl[48 + m];
    int gwave   = blockIdx.x * 4 + (tid >> 6);
    int nwaves  = gridDim.x * 4;
    int ngroups = (N + 15) >> 4;

    for (int g = gwave; g < ngroups; g += nwaves) {
        int base = g * 16;
        bool nv = (base + m) < N;
        int node = nv ? perm[base + m] : 0;
        int beg = nv ? beg_[node] : 0;   // 4 lanes per node share the address
        int deg = nv ? cnt_[node] : 0;

        // wave-max degree (uniform after sorting except at bin boundaries)
        int md = deg;
        md = max(md, __shfl_xor(md, 1, 64));
        md = max(md, __shfl_xor(md, 2, 64));
        md = max(md, __shfl_xor(md, 4, 64));
        md = max(md, __shfl_xor(md, 8, 64));

        float f0[8], f1[8];
#pragma unroll
        for (int u = 0; u < 8; ++u) { f0[u] = 0.f; f1[u] = 0.f; }

#pragma unroll 4
        for (int j = 0; j < md; ++j) {
            int idx = beg + ((j < deg) ? j : 0);
            int si = srclist[idx];
            const ushort* rp = inh + (size_t)si * D;
            short8 lo = *(const short8*)(rp + q * 8);        // features q*8..+7
            short8 hi = *(const short8*)(rp + 32 + q * 8);   // features 32+q*8..+7
            float msk = (j < deg) ? 1.f : 0.f;
#pragma unroll
            for (int u = 0; u < 8; ++u) {
                f0[u] = fmaf(msk, bf2f((ushort)lo[u]), f0[u]);
                f1[u] = fmaf(msk, bf2f((ushort)hi[u]), f1[u]);
            }
        }

        float scale = (deg > 0) ? 1.0f / (float)deg : 0.0f;
        short8 a0, a1;
#pragma unroll
        for (int u = 0; u < 8; ++u) {
            a0[u] = (short)f2bf(f0[u] * scale);
            a1[u] = (short)f2bf(f1[u] * scale);
        }

        // root rows load directly as A-fragments
        const ushort* rr = inh + (size_t)node * D;
        short8 r0 = *(const short8*)(rr + q * 8);
        short8 r1 = *(const short8*)(rr + 32 + q * 8);

#pragma unroll
        for (int c = 0; c < 4; ++c) {
            float bc = (c == 0) ? b0 : (c == 1) ? b1 : (c == 2) ? b2 : b3;
            floatx4 acc = {bc, bc, bc, bc};
            acc = __builtin_amdgcn_mfma_f32_16x16x32_bf16(a0, fL[c * 2 + 0][lane], acc, 0, 0, 0);
            acc = __builtin_amdgcn_mfma_f32_16x16x32_bf16(a1, fL[c * 2 + 1][lane], acc, 0, 0, 0);
            acc = __builtin_amdgcn_mfma_f32_16x16x32_bf16(r0, fR[c * 2 + 0][lane], acc, 0, 0, 0);
            acc = __builtin_amdgcn_mfma_f32_16x16x32_bf16(r1, fR[c * 2 + 1][lane], acc, 0, 0, 0);
#pragma unroll
            for (int r = 0; r < 4; ++r) {
                float v = acc[r];
                if (relu) v = fmaxf(v, 0.f);
                if (base + q * 4 + r < N) {
                    int onode = __shfl(node, q * 4 + r, 64);   // D row = q*4 + reg
                    size_t off = (size_t)onode * D + c * 16 + m;   // D col = lane&15
                    if (out_bf) out_bf[off] = f2bf(v);
                    else        out_f32[off] = v;
                }
            }
        }
    }
}

extern "C" void kernel_launch(void* const* d_in, const int* in_sizes, int n_in,
                              void* d_out, int out_size, void* d_ws, size_t ws_size,
                              hipStream_t stream) {
    const float* x   = (const float*)d_in[0];
    const int*   ei  = (const int*)d_in[1];
    const float* W1l = (const float*)d_in[2];
    const float* b1l = (const float*)d_in[3];
    const float* W1r = (const float*)d_in[4];
    const float* W2l = (const float*)d_in[5];
    const float* b2l = (const float*)d_in[6];
    const float* W2r = (const float*)d_in[7];
    float* out = (float*)d_out;

    int N = in_sizes[0] / D;   // 100000
    int E = in_sizes[1] / 2;   // 1000000

    char* ws = (char*)d_ws;
    // Layout (bytes):
    //   [0, N*D*2)         xh : bf16 x rows
    //   [N*D*2, 2*N*D*2)   hh : bf16 h rows; build-phase head/next alias here
    //   then srclist (+slack), beg, cnt, perm, total, hist, bincur
    ushort* xh = (ushort*)ws;
    ushort* hh = xh + (size_t)N * D;
    int*   head  = (int*)hh;                              // N ints (alias hh)
    int*   next  = head + N;                              // E ints (alias hh)
    int*   srclist = (int*)(ws + (size_t)2 * N * D * 2);  // E ints + 64 slack
    int*   beg    = srclist + E + 64;                     // N ints
    int*   cnt    = beg + N;                              // N ints
    int*   perm   = cnt + N;                              // N ints
    int*   total  = perm + N;                             // 1 int
    int*   hist   = total + 1;                            // 64 ints
    int*   bincur = hist + 64;                            // 64 ints

    int n4 = N * D / 4;
    cast_kernel<<<(n4 + 255) / 256, 256, 0, stream>>>(x, xh, head, hist, total, n4, N);

    int eblocks = (E + 255) / 256;
    int nblocks = (N + 255) / 256;
    build_kernel<<<eblocks, 256, 0, stream>>>(ei, head, next, E);
    alloc_fill_kernel<<<nblocks, 256, 0, stream>>>(ei, head, next, beg, cnt,
                                                   srclist, total, hist, N);
    binscan_kernel<<<1, 64, 0, stream>>>(hist, bincur);
    scatter_kernel<<<nblocks, 256, 0, stream>>>(cnt, bincur, perm, N);

    int ngroups = (N + 15) / 16;              // 6250
    int sblocks = (ngroups + 3) / 4;          // 1 group per wave
    // layer 1: hh(bf16) = relu(mean_agg(xh)@W1l^T + b1l + xh@W1r^T)
    sage_kernel<<<sblocks, 256, 0, stream>>>(xh, perm, beg, cnt, srclist,
                                             W1l, b1l, W1r, nullptr, hh, N, 1);
    // layer 2: out(fp32) = mean_agg(hh)@W2l^T + b2l + hh@W2r^T
    sage_kernel<<<sblocks, 256, 0, stream>>>(hh, perm, beg, cnt, srclist,
                                             W2l, b2l, W2r, out, nullptr, N, 0);
}

// Round 10
// 269.653 us; speedup vs baseline: 1.7884x; 1.0300x over previous
//
#include <hip/hip_runtime.h>

#define D 64

typedef __attribute__((ext_vector_type(8))) short short8;   // 8 bf16 = 4 VGPRs
typedef __attribute__((ext_vector_type(4))) float floatx4;  // MFMA C/D

__device__ __forceinline__ ushort f2bf(float f) {     // fp32 -> bf16, RNE
    unsigned u = __float_as_uint(f);
    u += 0x7fffu + ((u >> 16) & 1u);
    return (ushort)(u >> 16);
}
__device__ __forceinline__ float bf2f(ushort h) {
    return __int_as_float(((unsigned)h) << 16);
}

// ---------------- cast x to bf16 rows + init head/hist/bincur0/total ----------------
__global__ void cast_kernel(const float* __restrict__ x, ushort* __restrict__ xh,
                            int* __restrict__ head, int* __restrict__ hist,
                            int* __restrict__ bincur0, int* __restrict__ total,
                            int n4, int N) {
    int i = blockIdx.x * blockDim.x + threadIdx.x;
    if (i < N) head[i] = -1;
    if (i < 64) { hist[i] = 0; bincur0[i] = 0; }
    if (i == 0) *total = 0;
    if (i >= n4) return;
    float4 v = ((const float4*)x)[i];
    ushort4 r;
    r.x = f2bf(v.x); r.y = f2bf(v.y); r.z = f2bf(v.z); r.w = f2bf(v.w);
    ((ushort4*)xh)[i] = r;
}

// ---------------- build: linked list, exch-only, {src,next} packed ----------------
__global__ void build_kernel(const int* __restrict__ ei, int* __restrict__ head,
                             int2* __restrict__ edge2, int E) {
    int e = blockIdx.x * blockDim.x + threadIdx.x;
    if (e < E) {
        int src = ei[e];
        int prev = atomicExch(&head[ei[E + e]], e);
        edge2[e] = make_int2(src, prev);
    }
}

// ---------------- alloc+fill (+ degree histogram) ----------------
// count walk warms edge2 lines; fill walk re-reads them (one scattered line/hop).
__global__ void alloc_fill_kernel(const int2* __restrict__ edge2, const int* __restrict__ head,
                                  int* __restrict__ beg_out, int* __restrict__ cnt_out,
                                  int* __restrict__ srclist, int* __restrict__ total,
                                  int* __restrict__ hist, int N) {
    __shared__ int lh[64];
    int tid = threadIdx.x;
    if (tid < 64) lh[tid] = 0;
    __syncthreads();
    int i = blockIdx.x * blockDim.x + tid;
    int lane = tid & 63;
    int h = (i < N) ? head[i] : -1;
    int c = 0;
    for (int e = h; e >= 0; e = edge2[e].y) ++c;
    if (i < N) atomicAdd(&lh[c < 63 ? c : 63], 1);
    int p = c;
#pragma unroll
    for (int o = 1; o < 64; o <<= 1) {
        int u = __shfl_up(p, o, 64);
        if (lane >= o) p += u;
    }
    int wavetot = __shfl(p, 63, 64);
    int base = 0;
    if (lane == 63) base = atomicAdd(total, wavetot);
    base = __shfl(base, 63, 64);
    int b = base + p - c;
    if (i < N) { beg_out[i] = b; cnt_out[i] = c; }
    int ptr = b;
    for (int e = h; e >= 0;) {
        int2 sn = edge2[e];
        srclist[ptr++] = sn.x;
        e = sn.y;
    }
    __syncthreads();
    if (tid < 64 && lh[tid] > 0) atomicAdd(&hist[tid], lh[tid]);
}

// ---------------- scatter nodes into degree-sorted perm ----------------
// per-block redundant LDS scan of hist replaces the binscan dispatch.
__global__ void scatter_kernel(const int* __restrict__ cnt, const int* __restrict__ hist,
                               int* __restrict__ bincur0, int* __restrict__ perm, int N) {
    __shared__ int lh[64];
    __shared__ int lbase[64];
    __shared__ int sbase[64];
    int tid = threadIdx.x;
    if (tid < 64) {
        lh[tid] = 0;
        int c = hist[tid];
        int p = c;
#pragma unroll
        for (int o = 1; o < 64; o <<= 1) {
            int u = __shfl_up(p, o, 64);
            if (tid >= o) p += u;
        }
        sbase[tid] = p - c;   // exclusive prefix of bins
    }
    __syncthreads();
    int i = blockIdx.x * blockDim.x + tid;
    int bin = 0, slot = 0;
    if (i < N) {
        int c = cnt[i];
        bin = c < 63 ? c : 63;
        slot = atomicAdd(&lh[bin], 1);
    }
    __syncthreads();
    if (tid < 64 && lh[tid] > 0) lbase[tid] = sbase[tid] + atomicAdd(&bincur0[tid], lh[tid]);
    __syncthreads();
    if (i < N) perm[lbase[bin] + slot] = i;
}

// ---------------- fused SAGE layer: bf16 gather + MFMA combine ----------------
// 16 nodes per wave via degree-sorted perm (uniform degree -> md ~= deg).
// Lane L = (q=L>>4, m=L&15): gather accumulates the lane's MFMA A-frag features
// of node perm[base+m]; combine = 16 mfma_f32_16x16x32_bf16 with LDS B-frags.

__global__ void __launch_bounds__(256, 4) sage_kernel(
    const ushort* __restrict__ inh,      // bf16 rows [N][64]
    const int* __restrict__ perm,
    const int* __restrict__ beg_, const int* __restrict__ cnt_,
    const int* __restrict__ srclist,
    const float* __restrict__ Wl, const float* __restrict__ bl,
    const float* __restrict__ Wr,
    float* __restrict__ out_f32,         // fp32 out (layer 2) or null
    ushort* __restrict__ out_bf,         // bf16 out (layer 1) or null
    int N, int relu) {
    __shared__ short8 fL[8][64];   // [c*2+s][lane]: B-frag of Wl^T, col-tile c, k-step s
    __shared__ short8 fR[8][64];
    int tid = threadIdx.x;
    int lane = tid & 63;
    {
        int c = tid >> 6;
        int n = lane & 15;
        int q = lane >> 4;
#pragma unroll
        for (int s = 0; s < 2; ++s) {
            const float* pl = Wl + (c * 16 + n) * D + s * 32 + q * 8;
            const float* pr = Wr + (c * 16 + n) * D + s * 32 + q * 8;
            short8 vl, vr;
#pragma unroll
            for (int j = 0; j < 8; ++j) {
                vl[j] = (short)f2bf(pl[j]);
                vr[j] = (short)f2bf(pr[j]);
            }
            fL[c * 2 + s][lane] = vl;
            fR[c * 2 + s][lane] = vr;
        }
    }
    __syncthreads();

    int m = lane & 15;
    int q = lane >> 4;
    float b0 = bl[m], b1 = bl[16 + m], b2 = bl[32 + m], b3 = bl[48 + m];
    int gwave   = blockIdx.x * 4 + (tid >> 6);
    int nwaves  = gridDim.x * 4;
    int ngroups = (N + 15) >> 4;

    for (int g = gwave; g < ngroups; g += nwaves) {
        int base = g * 16;
        bool nv = (base + m) < N;
        int node = nv ? perm[base + m] : 0;
        int beg = nv ? beg_[node] : 0;   // 4 lanes per node share the address
        int deg = nv ? cnt_[node] : 0;

        // wave-max degree (uniform after sorting except at bin boundaries)
        int md = deg;
        md = max(md, __shfl_xor(md, 1, 64));
        md = max(md, __shfl_xor(md, 2, 64));
        md = max(md, __shfl_xor(md, 4, 64));
        md = max(md, __shfl_xor(md, 8, 64));

        float f0[8], f1[8];
#pragma unroll
        for (int u = 0; u < 8; ++u) { f0[u] = 0.f; f1[u] = 0.f; }

#pragma unroll 8
        for (int j = 0; j < md; ++j) {
            int idx = beg + ((j < deg) ? j : 0);
            int si = srclist[idx];
            const ushort* rp = inh + (size_t)si * D;
            short8 lo = *(const short8*)(rp + q * 8);        // features q*8..+7
            short8 hi = *(const short8*)(rp + 32 + q * 8);   // features 32+q*8..+7
            float msk = (j < deg) ? 1.f : 0.f;
#pragma unroll
            for (int u = 0; u < 8; ++u) {
                f0[u] = fmaf(msk, bf2f((ushort)lo[u]), f0[u]);
                f1[u] = fmaf(msk, bf2f((ushort)hi[u]), f1[u]);
            }
        }

        float scale = (deg > 0) ? 1.0f / (float)deg : 0.0f;
        short8 a0, a1;
#pragma unroll
        for (int u = 0; u < 8; ++u) {
            a0[u] = (short)f2bf(f0[u] * scale);
            a1[u] = (short)f2bf(f1[u] * scale);
        }

        // root rows load directly as A-fragments
        const ushort* rr = inh + (size_t)node * D;
        short8 r0 = *(const short8*)(rr + q * 8);
        short8 r1 = *(const short8*)(rr + 32 + q * 8);

#pragma unroll
        for (int c = 0; c < 4; ++c) {
            float bc = (c == 0) ? b0 : (c == 1) ? b1 : (c == 2) ? b2 : b3;
            floatx4 acc = {bc, bc, bc, bc};
            acc = __builtin_amdgcn_mfma_f32_16x16x32_bf16(a0, fL[c * 2 + 0][lane], acc, 0, 0, 0);
            acc = __builtin_amdgcn_mfma_f32_16x16x32_bf16(a1, fL[c * 2 + 1][lane], acc, 0, 0, 0);
            acc = __builtin_amdgcn_mfma_f32_16x16x32_bf16(r0, fR[c * 2 + 0][lane], acc, 0, 0, 0);
            acc = __builtin_amdgcn_mfma_f32_16x16x32_bf16(r1, fR[c * 2 + 1][lane], acc, 0, 0, 0);
#pragma unroll
            for (int r = 0; r < 4; ++r) {
                float v = acc[r];
                if (relu) v = fmaxf(v, 0.f);
                if (base + q * 4 + r < N) {
                    int onode = __shfl(node, q * 4 + r, 64);   // D row = q*4 + reg
                    size_t off = (size_t)onode * D + c * 16 + m;   // D col = lane&15
                    if (out_bf) out_bf[off] = f2bf(v);
                    else        out_f32[off] = v;
                }
            }
        }
    }
}

extern "C" void kernel_launch(void* const* d_in, const int* in_sizes, int n_in,
                              void* d_out, int out_size, void* d_ws, size_t ws_size,
                              hipStream_t stream) {
    const float* x   = (const float*)d_in[0];
    const int*   ei  = (const int*)d_in[1];
    const float* W1l = (const float*)d_in[2];
    const float* b1l = (const float*)d_in[3];
    const float* W1r = (const float*)d_in[4];
    const float* W2l = (const float*)d_in[5];
    const float* b2l = (const float*)d_in[6];
    const float* W2r = (const float*)d_in[7];
    float* out = (float*)d_out;

    int N = in_sizes[0] / D;   // 100000
    int E = in_sizes[1] / 2;   // 1000000

    char* ws = (char*)d_ws;
    // Layout (bytes):
    //   [0, N*D*2)         xh : bf16 x rows
    //   [N*D*2, 2*N*D*2)   hh : bf16 h rows; build-phase head/edge2 alias here
    //                          (head 400KB + edge2 8MB < 12.8MB; dead before sage1)
    //   then srclist (+slack), beg, cnt, perm, total, hist, bincur0
    ushort* xh = (ushort*)ws;
    ushort* hh = xh + (size_t)N * D;
    int*   head  = (int*)hh;                              // N ints (alias hh)
    int2*  edge2 = (int2*)((char*)hh + (size_t)((N + 1) & ~1) * 4); // E int2 (alias hh)
    int*   srclist = (int*)(ws + (size_t)2 * N * D * 2);  // E ints + 64 slack
    int*   beg     = srclist + E + 64;                    // N ints
    int*   cnt     = beg + N;                             // N ints
    int*   perm    = cnt + N;                             // N ints
    int*   total   = perm + N;                            // 1 int
    int*   hist    = total + 1;                           // 64 ints
    int*   bincur0 = hist + 64;                           // 64 ints

    int n4 = N * D / 4;
    cast_kernel<<<(n4 + 255) / 256, 256, 0, stream>>>(x, xh, head, hist, bincur0,
                                                      total, n4, N);

    int eblocks = (E + 255) / 256;
    int nblocks = (N + 255) / 256;
    build_kernel<<<eblocks, 256, 0, stream>>>(ei, head, edge2, E);
    alloc_fill_kernel<<<nblocks, 256, 0, stream>>>(edge2, head, beg, cnt,
                                                   srclist, total, hist, N);
    scatter_kernel<<<nblocks, 256, 0, stream>>>(cnt, hist, bincur0, perm, N);

    int ngroups = (N + 15) / 16;              // 6250
    int sblocks = (ngroups + 3) / 4;          // 1 group per wave
    // layer 1: hh(bf16) = relu(mean_agg(xh)@W1l^T + b1l + xh@W1r^T)
    sage_kernel<<<sblocks, 256, 0, stream>>>(xh, perm, beg, cnt, srclist,
                                             W1l, b1l, W1r, nullptr, hh, N, 1);
    // layer 2: out(fp32) = mean_agg(hh)@W2l^T + b2l + hh@W2r^T
    sage_kernel<<<sblocks, 256, 0, stream>>>(hh, perm, beg, cnt, srclist,
                                             W2l, b2l, W2r, out, nullptr, N, 0);
}